// Round 9
// baseline (280.211 us; speedup 1.0000x reference)
//
#include <hip/hip_runtime.h>
#include <hip/hip_fp16.h>
#include <stdint.h>

typedef _Float16 half_t;
typedef half_t half8 __attribute__((ext_vector_type(8)));
typedef float f32x4 __attribute__((ext_vector_type(4)));

#define E4M3_MAX 448.0f
#define MFMA16 __builtin_amdgcn_mfma_f32_16x16x32_f16

// problem shape (guarded in kernel_launch)
constexpr int Mdim = 8192, Ndim = 4096, Kdim = 4096;
constexpr int NKT = Kdim / 64;     // 64 K-tiles of 64
constexpr int NITER = NKT / 2;     // 32 iterations (2 K-tiles each)
constexpr int NTN = Ndim / 256;    // 16 N-tiles
constexpr int NTM = Mdim / 256;    // 32 M-tiles
constexpr int LDS_BYTES = 131072;

// ---------------------------------------------------------------------------
// Merged quantization kernel (round-8, passed): x and w in one launch.
// Writes DEQUANTIZED fp16: dq = fp16(clip(round(v/s), +-448) * s).
// ---------------------------------------------------------------------------
__global__ __launch_bounds__(256) void quant_kernel(const float* __restrict__ xin,
                                                    const float* __restrict__ win,
                                                    half_t* __restrict__ xq,
                                                    half_t* __restrict__ wq,
                                                    int C) {
    const int cb = blockIdx.x;
    int rb = blockIdx.y;
    const float* in;
    half_t* outq;
    if (rb < Mdim / 128) {
        in = xin; outq = xq;
    } else {
        rb -= Mdim / 128;
        in = win; outq = wq;
    }
    const int tid = threadIdx.x;
    const int col4 = tid & 31;
    const int rsub = tid >> 5;

    const float* base = in + (size_t)(rb * 128 + rsub) * C + cb * 128 + col4 * 4;

    f32x4 v[16];
    float amax = 0.0f;
#pragma unroll
    for (int p = 0; p < 16; ++p) {
        v[p] = *(const f32x4*)(base + (size_t)p * 8 * C);
        amax = fmaxf(amax, fmaxf(fmaxf(fabsf(v[p].x), fabsf(v[p].y)),
                                 fmaxf(fabsf(v[p].z), fabsf(v[p].w))));
    }
#pragma unroll
    for (int off = 32; off > 0; off >>= 1)
        amax = fmaxf(amax, __shfl_xor(amax, off, 64));
    __shared__ float red[4];
    if ((tid & 63) == 0) red[tid >> 6] = amax;
    __syncthreads();
    amax = fmaxf(fmaxf(red[0], red[1]), fmaxf(red[2], red[3]));

    const float scale = fmaxf(amax / E4M3_MAX, 1e-8f);
    const float rs = 1.0f / scale;

    half_t* obase = outq + (size_t)(rb * 128 + rsub) * C + cb * 128 + col4 * 4;
#pragma unroll
    for (int p = 0; p < 16; ++p) {
        float q0 = fminf(fmaxf(rintf(v[p].x * rs), -E4M3_MAX), E4M3_MAX) * scale;
        float q1 = fminf(fmaxf(rintf(v[p].y * rs), -E4M3_MAX), E4M3_MAX) * scale;
        float q2 = fminf(fmaxf(rintf(v[p].z * rs), -E4M3_MAX), E4M3_MAX) * scale;
        float q3 = fminf(fmaxf(rintf(v[p].w * rs), -E4M3_MAX), E4M3_MAX) * scale;
        union { half_t h[4]; uint64_t u; } pk;
        pk.h[0] = (half_t)q0; pk.h[1] = (half_t)q1;
        pk.h[2] = (half_t)q2; pk.h[3] = (half_t)q3;
        *(uint64_t*)(obase + (size_t)p * 8 * C) = pk.u;
    }
}

// ---------------------------------------------------------------------------
// fp16 256x256 8-phase GEMM. Identical segments/stages/gates to round 5
// (race-verified R4), with ONE intra-segment change: ds_reads issue BEFORE
// the MFMA cluster so the LDS pipe drains under the matrix pipe.
// Requires double A-frag register sets (ax/ay, alternating by phase parity).
// ---------------------------------------------------------------------------
__device__ __forceinline__ void async16(const half_t* g, char* l) {
    __builtin_amdgcn_global_load_lds((const __attribute__((address_space(1))) void*)g,
                                     (__attribute__((address_space(3))) void*)l, 16, 0, 0);
}

extern __shared__ char smem[];

__global__ __launch_bounds__(512, 2) void gemm_kernel(
    const half_t* __restrict__ A, const half_t* __restrict__ B,
    const float* __restrict__ bias, float* __restrict__ C) {

    const int tid = threadIdx.x;
    const int lane = tid & 63;
    const int wid = tid >> 6;          // 0..7
    const int lo = lane & 15, hi = lane >> 4;
    const int wr = wid >> 2;           // 0..1  (M side)
    const int wc = wid & 3;            // 0..3  (N side)

    // XCD-aware swizzle; nwg = 512, divisible by 8
    const int bid = blockIdx.x;
    constexpr int cpx = (NTM * NTN) / 8;
    const int id = (bid & 7) * cpx + (bid >> 3);
    const int tm = id / NTN, tn = id % NTN;

    // ---- staging source bases (pre-swizzled global k; LDS dest linear) ----
    const int r0 = tid >> 3;                          // 0..63
    const int ks = ((tid & 7) ^ (r0 & 7)) * 8;        // swizzled k-elem offset
    const half_t* Abase = A + (size_t)(tm * 256 + r0) * Kdim + ks;
    const half_t* Bbase = B + (size_t)(tn * 256 + r0) * Kdim + ks;
    char* ldstA = smem + tid * 16;
    char* ldstB = smem + 65536 + tid * 16;

#define STG_AS(b, s, kt)                                                                  \
    async16(Abase + (size_t)((s) * 64) * Kdim + (kt) * 64,                                \
            ldstA + (b) * 32768 + (s) * 8192)
#define STG_B(b, h, kt) do {                                                              \
    async16(Bbase + (size_t)((h) * 128) * Kdim + (kt) * 64,                               \
            ldstB + (b) * 32768 + (h) * 16384);                                           \
    async16(Bbase + (size_t)((h) * 128 + 64) * Kdim + (kt) * 64,                          \
            ldstB + (b) * 32768 + (h) * 16384 + 8192); } while (0)

    // ---- prologue stages: buf0 full (kt0) + B-buf1 (kt1) ----
    STG_B(0, 0, 0); STG_B(0, 1, 0);
    STG_AS(0, 0, 0); STG_AS(0, 1, 0); STG_AS(0, 2, 0); STG_AS(0, 3, 0);
    STG_B(1, 0, 1); STG_B(1, 1, 1);
    asm volatile("s_waitcnt vmcnt(4)" ::: "memory");   // buf0 landed; B-buf1 in flight
    __builtin_amdgcn_sched_barrier(0);
    __builtin_amdgcn_s_barrier();
    __builtin_amdgcn_sched_barrier(0);

    // ---- ds_read lane bases (XOR-swizzled; 0 conflicts measured r1-r5) ----
    const int koff0 = ((hi ^ (lo & 3)) << 4) + (((lo >> 2) & 1) << 6);
    const char* pA0 = smem + wr * 16384 + lo * 128 + koff0;
    const char* pA1 = smem + wr * 16384 + lo * 128 + (koff0 ^ 64);
    const char* pB0 = smem + 65536 + wc * 8192 + lo * 128 + koff0;
    const char* pB1 = smem + 65536 + wc * 8192 + lo * 128 + (koff0 ^ 64);

    f32x4 acc[8][4] = {};
    half8 bfr[4][2];
    half8 ax0, ax1, ax2, ax3;   // A-frag set X (phases 0,2)
    half8 ay0, ay1, ay2, ay3;   // A-frag set Y (phases 1,3)

#define BARSEQ                                                                            \
    __builtin_amdgcn_sched_barrier(0);                                                    \
    __builtin_amdgcn_s_barrier();                                                         \
    __builtin_amdgcn_sched_barrier(0);

#define LDA4(b, q, R0, R1, R2, R3)                                                        \
    R0 = *(const half8*)(pA0 + (b) * 32768 + (q) * 4096);                                 \
    R1 = *(const half8*)(pA1 + (b) * 32768 + (q) * 4096);                                 \
    R2 = *(const half8*)(pA0 + (b) * 32768 + (q) * 4096 + 2048);                          \
    R3 = *(const half8*)(pA1 + (b) * 32768 + (q) * 4096 + 2048);

#define LDB8(b)                                                                           \
    bfr[0][0] = *(const half8*)(pB0 + (b) * 32768 + 0 * 2048);                            \
    bfr[0][1] = *(const half8*)(pB1 + (b) * 32768 + 0 * 2048);                            \
    bfr[1][0] = *(const half8*)(pB0 + (b) * 32768 + 1 * 2048);                            \
    bfr[1][1] = *(const half8*)(pB1 + (b) * 32768 + 1 * 2048);                            \
    bfr[2][0] = *(const half8*)(pB0 + (b) * 32768 + 2 * 2048);                            \
    bfr[2][1] = *(const half8*)(pB1 + (b) * 32768 + 2 * 2048);                            \
    bfr[3][0] = *(const half8*)(pB0 + (b) * 32768 + 3 * 2048);                            \
    bfr[3][1] = *(const half8*)(pB1 + (b) * 32768 + 3 * 2048);

#define MFMAQ(q, A00, A01, A10, A11)                                                      \
    __builtin_amdgcn_s_setprio(1);                                                        \
    acc[2*(q)][0]   = MFMA16(A00, bfr[0][0], acc[2*(q)][0],   0, 0, 0);                   \
    acc[2*(q)][1]   = MFMA16(A00, bfr[1][0], acc[2*(q)][1],   0, 0, 0);                   \
    acc[2*(q)][2]   = MFMA16(A00, bfr[2][0], acc[2*(q)][2],   0, 0, 0);                   \
    acc[2*(q)][3]   = MFMA16(A00, bfr[3][0], acc[2*(q)][3],   0, 0, 0);                   \
    acc[2*(q)+1][0] = MFMA16(A10, bfr[0][0], acc[2*(q)+1][0], 0, 0, 0);                   \
    acc[2*(q)+1][1] = MFMA16(A10, bfr[1][0], acc[2*(q)+1][1], 0, 0, 0);                   \
    acc[2*(q)+1][2] = MFMA16(A10, bfr[2][0], acc[2*(q)+1][2], 0, 0, 0);                   \
    acc[2*(q)+1][3] = MFMA16(A10, bfr[3][0], acc[2*(q)+1][3], 0, 0, 0);                   \
    acc[2*(q)][0]   = MFMA16(A01, bfr[0][1], acc[2*(q)][0],   0, 0, 0);                   \
    acc[2*(q)][1]   = MFMA16(A01, bfr[1][1], acc[2*(q)][1],   0, 0, 0);                   \
    acc[2*(q)][2]   = MFMA16(A01, bfr[2][1], acc[2*(q)][2],   0, 0, 0);                   \
    acc[2*(q)][3]   = MFMA16(A01, bfr[3][1], acc[2*(q)][3],   0, 0, 0);                   \
    acc[2*(q)+1][0] = MFMA16(A11, bfr[0][1], acc[2*(q)+1][0], 0, 0, 0);                   \
    acc[2*(q)+1][1] = MFMA16(A11, bfr[1][1], acc[2*(q)+1][1], 0, 0, 0);                   \
    acc[2*(q)+1][2] = MFMA16(A11, bfr[2][1], acc[2*(q)+1][2], 0, 0, 0);                   \
    acc[2*(q)+1][3] = MFMA16(A11, bfr[3][1], acc[2*(q)+1][3], 0, 0, 0);                   \
    __builtin_amdgcn_s_setprio(0);

    // ---- peeled seg P1 of iter 0 (no MFMA yet) ----
    LDB8(0)
    LDA4(0, 0, ax0, ax1, ax2, ax3)
    STG_AS(1, 0, 1); STG_AS(1, 2, 1);
    BARSEQ

    for (int i = 0; i < NITER; ++i) {
        const int kA1  = 2 * i + 1;
        const int ktn0 = (2 * i + 2) & (NKT - 1);  // wraps on last iter -> dead
        const int ktn1 = (2 * i + 3) & (NKT - 1);

        // ---- seg P2: reads first, then MFMA(P1) ----
        LDA4(0, 1, ay0, ay1, ay2, ay3)
        MFMAQ(0, ax0, ax1, ax2, ax3)
        STG_AS(1, 1, kA1); STG_AS(1, 3, kA1);
        BARSEQ
        // ---- seg P3 ----
        LDA4(0, 2, ax0, ax1, ax2, ax3)
        MFMAQ(1, ay0, ay1, ay2, ay3)
        STG_B(0, 0, ktn0);
        BARSEQ
        // ---- seg P4 (+gate: buf1 fully landed) ----
        LDA4(0, 3, ay0, ay1, ay2, ay3)
        MFMAQ(2, ax0, ax1, ax2, ax3)
        STG_B(0, 1, ktn0);
        asm volatile("s_waitcnt vmcnt(4)" ::: "memory");
        BARSEQ
        // ---- seg P5: A-read early; B-reload after MFMA (WAR on bfr) ----
        LDA4(1, 0, ax0, ax1, ax2, ax3)
        MFMAQ(3, ay0, ay1, ay2, ay3)
        LDB8(1)
        STG_AS(0, 0, ktn0); STG_AS(0, 2, ktn0);
        BARSEQ
        // ---- seg P6 ----
        LDA4(1, 1, ay0, ay1, ay2, ay3)
        MFMAQ(0, ax0, ax1, ax2, ax3)
        STG_AS(0, 1, ktn0); STG_AS(0, 3, ktn0);
        BARSEQ
        // ---- seg P7 ----
        LDA4(1, 2, ax0, ax1, ax2, ax3)
        MFMAQ(1, ay0, ay1, ay2, ay3)
        STG_B(1, 0, ktn1);
        BARSEQ
        // ---- seg P8 (+gate: buf0' fully landed) ----
        LDA4(1, 3, ay0, ay1, ay2, ay3)
        MFMAQ(2, ax0, ax1, ax2, ax3)
        STG_B(1, 1, ktn1);
        asm volatile("s_waitcnt vmcnt(4)" ::: "memory");
        BARSEQ
        // ---- seg P1 of iter i+1 (tail: only the final MFMA) ----
        if (i + 1 < NITER) {
            LDA4(0, 0, ax0, ax1, ax2, ax3)
            MFMAQ(3, ay0, ay1, ay2, ay3)
            LDB8(0)
            STG_AS(1, 0, 2 * i + 3); STG_AS(1, 2, 2 * i + 3);
            BARSEQ
        } else {
            MFMAQ(3, ay0, ay1, ay2, ay3)
        }
    }

    // drain in-flight dead stages before workgroup teardown
    asm volatile("s_waitcnt vmcnt(0)" ::: "memory");

    // ---- epilogue: bias + fp32 store (acc[m] row = 128wr + 16m + 4hi + r) ----
    const int rbase = tm * 256 + wr * 128;
    const int cbase = tn * 256 + wc * 64;
    float bv0 = bias[cbase + 0 * 16 + lo];
    float bv1 = bias[cbase + 1 * 16 + lo];
    float bv2 = bias[cbase + 2 * 16 + lo];
    float bv3 = bias[cbase + 3 * 16 + lo];
#pragma unroll
    for (int m = 0; m < 8; ++m) {
        const int r0r = rbase + m * 16 + hi * 4;
#pragma unroll
        for (int r = 0; r < 4; ++r) {
            float* crow = C + (size_t)(r0r + r) * Ndim + cbase + lo;
            crow[0]  = acc[m][0][r] + bv0;
            crow[16] = acc[m][1][r] + bv1;
            crow[32] = acc[m][2][r] + bv2;
            crow[48] = acc[m][3][r] + bv3;
        }
    }
}

// ---------------------------------------------------------------------------
extern "C" void kernel_launch(void* const* d_in, const int* in_sizes, int n_in,
                              void* d_out, int out_size, void* d_ws, size_t ws_size,
                              hipStream_t stream) {
    const float* x = (const float*)d_in[0];
    const float* w = (const float*)d_in[1];
    const float* bias = (const float*)d_in[2];
    float* out = (float*)d_out;

    if (in_sizes[2] != Ndim || in_sizes[1] != Ndim * Kdim || in_sizes[0] != Mdim * Kdim)
        return;  // shape-specialized; fail loudly

    const size_t xq_bytes = (size_t)Mdim * Kdim * sizeof(half_t);
    const size_t wq_bytes = (size_t)Ndim * Kdim * sizeof(half_t);
    if (ws_size < xq_bytes + wq_bytes) return;

    half_t* xq = (half_t*)d_ws;
    half_t* wq = (half_t*)((char*)d_ws + xq_bytes);

    quant_kernel<<<dim3(Kdim / 128, Mdim / 128 + Ndim / 128), 256, 0, stream>>>(
        x, w, xq, wq, Kdim);

    (void)hipFuncSetAttribute((const void*)gemm_kernel,
                              hipFuncAttributeMaxDynamicSharedMemorySize, LDS_BYTES);

    gemm_kernel<<<dim3(NTM * NTN), dim3(512), LDS_BYTES, stream>>>(xq, wq, bias, out);
}

// Round 10
// 273.209 us; speedup vs baseline: 1.0256x; 1.0256x over previous
//
#include <hip/hip_runtime.h>
#include <hip/hip_fp16.h>
#include <stdint.h>

typedef _Float16 half_t;
typedef half_t half8 __attribute__((ext_vector_type(8)));
typedef float f32x4 __attribute__((ext_vector_type(4)));

#define E4M3_MAX 448.0f
#define MFMA16 __builtin_amdgcn_mfma_f32_16x16x32_f16

// problem shape (guarded in kernel_launch)
constexpr int Mdim = 8192, Ndim = 4096, Kdim = 4096;
constexpr int NKT = Kdim / 64;     // 64 K-tiles of 64
constexpr int NITER = NKT / 2;     // 32 iterations (2 K-tiles each)
constexpr int NTN = Ndim / 256;    // 16 N-tiles
constexpr int NTM = Mdim / 256;    // 32 M-tiles
constexpr int LDS_BYTES = 131072;

// ---------------------------------------------------------------------------
// Merged quantization kernel (round-8, measured best): x and w in one launch.
// blockIdx.y in [0, M/128) -> x row-block; [M/128, M/128+N/128) -> w row-block.
// Writes DEQUANTIZED fp16: dq = fp16(clip(round(v/s), +-448) * s).
// ---------------------------------------------------------------------------
__global__ __launch_bounds__(256) void quant_kernel(const float* __restrict__ xin,
                                                    const float* __restrict__ win,
                                                    half_t* __restrict__ xq,
                                                    half_t* __restrict__ wq,
                                                    int C) {
    const int cb = blockIdx.x;
    int rb = blockIdx.y;
    const float* in;
    half_t* outq;
    if (rb < Mdim / 128) {
        in = xin; outq = xq;
    } else {
        rb -= Mdim / 128;
        in = win; outq = wq;
    }
    const int tid = threadIdx.x;
    const int col4 = tid & 31;
    const int rsub = tid >> 5;

    const float* base = in + (size_t)(rb * 128 + rsub) * C + cb * 128 + col4 * 4;

    f32x4 v[16];
    float amax = 0.0f;
#pragma unroll
    for (int p = 0; p < 16; ++p) {
        v[p] = *(const f32x4*)(base + (size_t)p * 8 * C);
        amax = fmaxf(amax, fmaxf(fmaxf(fabsf(v[p].x), fabsf(v[p].y)),
                                 fmaxf(fabsf(v[p].z), fabsf(v[p].w))));
    }
#pragma unroll
    for (int off = 32; off > 0; off >>= 1)
        amax = fmaxf(amax, __shfl_xor(amax, off, 64));
    __shared__ float red[4];
    if ((tid & 63) == 0) red[tid >> 6] = amax;
    __syncthreads();
    amax = fmaxf(fmaxf(red[0], red[1]), fmaxf(red[2], red[3]));

    const float scale = fmaxf(amax / E4M3_MAX, 1e-8f);
    const float rs = 1.0f / scale;

    half_t* obase = outq + (size_t)(rb * 128 + rsub) * C + cb * 128 + col4 * 4;
#pragma unroll
    for (int p = 0; p < 16; ++p) {
        float q0 = fminf(fmaxf(rintf(v[p].x * rs), -E4M3_MAX), E4M3_MAX) * scale;
        float q1 = fminf(fmaxf(rintf(v[p].y * rs), -E4M3_MAX), E4M3_MAX) * scale;
        float q2 = fminf(fmaxf(rintf(v[p].z * rs), -E4M3_MAX), E4M3_MAX) * scale;
        float q3 = fminf(fmaxf(rintf(v[p].w * rs), -E4M3_MAX), E4M3_MAX) * scale;
        union { half_t h[4]; uint64_t u; } pk;
        pk.h[0] = (half_t)q0; pk.h[1] = (half_t)q1;
        pk.h[2] = (half_t)q2; pk.h[3] = (half_t)q3;
        *(uint64_t*)(obase + (size_t)p * 8 * C) = pk.u;
    }
}

// ---------------------------------------------------------------------------
// Pure fp16 256x256 8-phase GEMM — round-5 kernel VERBATIM (measured best:
// 224 us, MfmaUtil 58.5%, 0 bank conflicts, VGPR 112).
// 8 waves (2Mx4N), BK=64, 2 K-tiles/iter, A staged in 64-row slices with
// 2-phase read windows, uniform 2 global_load_lds per phase, counted
// vmcnt(4) gates at P4/P8 only, raw s_barrier (no vmcnt(0) drains in-loop),
// setprio(1) around MFMA clusters, XOR-swizzled LDS (pre-swizzled source).
// Race-freedom of the stage schedule verified in round 4.
// ---------------------------------------------------------------------------
__device__ __forceinline__ void async16(const half_t* g, char* l) {
    __builtin_amdgcn_global_load_lds((const __attribute__((address_space(1))) void*)g,
                                     (__attribute__((address_space(3))) void*)l, 16, 0, 0);
}

extern __shared__ char smem[];

__global__ __launch_bounds__(512, 2) void gemm_kernel(
    const half_t* __restrict__ A, const half_t* __restrict__ B,
    const float* __restrict__ bias, float* __restrict__ C) {

    const int tid = threadIdx.x;
    const int lane = tid & 63;
    const int wid = tid >> 6;          // 0..7
    const int lo = lane & 15, hi = lane >> 4;
    const int wr = wid >> 2;           // 0..1  (M side)
    const int wc = wid & 3;            // 0..3  (N side)

    // XCD-aware swizzle; nwg = 512, divisible by 8
    const int bid = blockIdx.x;
    constexpr int cpx = (NTM * NTN) / 8;
    const int id = (bid & 7) * cpx + (bid >> 3);
    const int tm = id / NTN, tn = id % NTN;

    // ---- staging source bases (pre-swizzled global k; LDS dest linear) ----
    const int r0 = tid >> 3;                          // 0..63
    const int ks = ((tid & 7) ^ (r0 & 7)) * 8;        // swizzled k-elem offset
    const half_t* Abase = A + (size_t)(tm * 256 + r0) * Kdim + ks;
    const half_t* Bbase = B + (size_t)(tn * 256 + r0) * Kdim + ks;
    char* ldstA = smem + tid * 16;
    char* ldstB = smem + 65536 + tid * 16;

    // A slice s (64 global rows) of K-tile kt -> buf b: ONE async16
#define STG_AS(b, s, kt)                                                                  \
    async16(Abase + (size_t)((s) * 64) * Kdim + (kt) * 64,                                \
            ldstA + (b) * 32768 + (s) * 8192)
    // B half h (128 rows) of K-tile kt -> buf b: TWO async16
#define STG_B(b, h, kt) do {                                                              \
    async16(Bbase + (size_t)((h) * 128) * Kdim + (kt) * 64,                               \
            ldstB + (b) * 32768 + (h) * 16384);                                           \
    async16(Bbase + (size_t)((h) * 128 + 64) * Kdim + (kt) * 64,                          \
            ldstB + (b) * 32768 + (h) * 16384 + 8192); } while (0)

    // ---- prologue: buf0 full (kt0), then B-buf1 (kt1); A-buf1 staged in-loop P1/P2 ----
    STG_B(0, 0, 0); STG_B(0, 1, 0);
    STG_AS(0, 0, 0); STG_AS(0, 1, 0); STG_AS(0, 2, 0); STG_AS(0, 3, 0);
    STG_B(1, 0, 1); STG_B(1, 1, 1);
    asm volatile("s_waitcnt vmcnt(4)" ::: "memory");   // buf0 landed; B-buf1 in flight
    __builtin_amdgcn_sched_barrier(0);
    __builtin_amdgcn_s_barrier();
    __builtin_amdgcn_sched_barrier(0);

    // ---- ds_read lane bases (XOR-swizzled; 0 conflicts measured r1-r5) ----
    const int koff0 = ((hi ^ (lo & 3)) << 4) + (((lo >> 2) & 1) << 6);
    const char* pA0 = smem + wr * 16384 + lo * 128 + koff0;
    const char* pA1 = smem + wr * 16384 + lo * 128 + (koff0 ^ 64);
    const char* pB0 = smem + 65536 + wc * 8192 + lo * 128 + koff0;
    const char* pB1 = smem + 65536 + wc * 8192 + lo * 128 + (koff0 ^ 64);

    f32x4 acc[8][4] = {};
    half8 bfr[4][2];

#define BARSEQ                                                                            \
    __builtin_amdgcn_sched_barrier(0);                                                    \
    __builtin_amdgcn_s_barrier();                                                         \
    __builtin_amdgcn_sched_barrier(0);

#define LDA4(b, q, A00, A01, A10, A11)                                                    \
    half8 A00 = *(const half8*)(pA0 + (b) * 32768 + (q) * 4096);                          \
    half8 A01 = *(const half8*)(pA1 + (b) * 32768 + (q) * 4096);                          \
    half8 A10 = *(const half8*)(pA0 + (b) * 32768 + (q) * 4096 + 2048);                   \
    half8 A11 = *(const half8*)(pA1 + (b) * 32768 + (q) * 4096 + 2048);

#define LDB8(b)                                                                           \
    bfr[0][0] = *(const half8*)(pB0 + (b) * 32768 + 0 * 2048);                            \
    bfr[0][1] = *(const half8*)(pB1 + (b) * 32768 + 0 * 2048);                            \
    bfr[1][0] = *(const half8*)(pB0 + (b) * 32768 + 1 * 2048);                            \
    bfr[1][1] = *(const half8*)(pB1 + (b) * 32768 + 1 * 2048);                            \
    bfr[2][0] = *(const half8*)(pB0 + (b) * 32768 + 2 * 2048);                            \
    bfr[2][1] = *(const half8*)(pB1 + (b) * 32768 + 2 * 2048);                            \
    bfr[3][0] = *(const half8*)(pB0 + (b) * 32768 + 3 * 2048);                            \
    bfr[3][1] = *(const half8*)(pB1 + (b) * 32768 + 3 * 2048);

#define MFMAQ(q, A00, A01, A10, A11)                                                      \
    __builtin_amdgcn_s_setprio(1);                                                        \
    acc[2*(q)][0]   = MFMA16(A00, bfr[0][0], acc[2*(q)][0],   0, 0, 0);                   \
    acc[2*(q)][1]   = MFMA16(A00, bfr[1][0], acc[2*(q)][1],   0, 0, 0);                   \
    acc[2*(q)][2]   = MFMA16(A00, bfr[2][0], acc[2*(q)][2],   0, 0, 0);                   \
    acc[2*(q)][3]   = MFMA16(A00, bfr[3][0], acc[2*(q)][3],   0, 0, 0);                   \
    acc[2*(q)+1][0] = MFMA16(A10, bfr[0][0], acc[2*(q)+1][0], 0, 0, 0);                   \
    acc[2*(q)+1][1] = MFMA16(A10, bfr[1][0], acc[2*(q)+1][1], 0, 0, 0);                   \
    acc[2*(q)+1][2] = MFMA16(A10, bfr[2][0], acc[2*(q)+1][2], 0, 0, 0);                   \
    acc[2*(q)+1][3] = MFMA16(A10, bfr[3][0], acc[2*(q)+1][3], 0, 0, 0);                   \
    acc[2*(q)][0]   = MFMA16(A01, bfr[0][1], acc[2*(q)][0],   0, 0, 0);                   \
    acc[2*(q)][1]   = MFMA16(A01, bfr[1][1], acc[2*(q)][1],   0, 0, 0);                   \
    acc[2*(q)][2]   = MFMA16(A01, bfr[2][1], acc[2*(q)][2],   0, 0, 0);                   \
    acc[2*(q)][3]   = MFMA16(A01, bfr[3][1], acc[2*(q)][3],   0, 0, 0);                   \
    acc[2*(q)+1][0] = MFMA16(A11, bfr[0][1], acc[2*(q)+1][0], 0, 0, 0);                   \
    acc[2*(q)+1][1] = MFMA16(A11, bfr[1][1], acc[2*(q)+1][1], 0, 0, 0);                   \
    acc[2*(q)+1][2] = MFMA16(A11, bfr[2][1], acc[2*(q)+1][2], 0, 0, 0);                   \
    acc[2*(q)+1][3] = MFMA16(A11, bfr[3][1], acc[2*(q)+1][3], 0, 0, 0);                   \
    __builtin_amdgcn_s_setprio(0);

    for (int i = 0; i < NITER; ++i) {
        const int kA1  = 2 * i + 1;                // A-buf1 content (read P5-P8 this iter)
        const int ktn0 = (2 * i + 2) & (NKT - 1);  // next buf0 (last iter: wraps -> dead)
        const int ktn1 = (2 * i + 3) & (NKT - 1);  // next buf1-B (wraps -> dead)

        // ---- P1: B(buf0) + A(buf0,q0); stage A1 slices 0,2 ----
        {
            LDB8(0)
            LDA4(0, 0, a00, a01, a10, a11)
            STG_AS(1, 0, kA1); STG_AS(1, 2, kA1);
            BARSEQ
            MFMAQ(0, a00, a01, a10, a11)
        }
        // ---- P2: A(buf0,q1); stage A1 slices 1,3 ----
        {
            LDA4(0, 1, a00, a01, a10, a11)
            STG_AS(1, 1, kA1); STG_AS(1, 3, kA1);
            BARSEQ
            MFMAQ(1, a00, a01, a10, a11)
        }
        // ---- P3: A(buf0,q2); stage B0h0' ----
        {
            LDA4(0, 2, a00, a01, a10, a11)
            STG_B(0, 0, ktn0);
            BARSEQ
            MFMAQ(2, a00, a01, a10, a11)
        }
        // ---- P4: A(buf0,q3); stage B0h1'; GATE vmcnt(4) -> buf1 fully landed ----
        {
            LDA4(0, 3, a00, a01, a10, a11)
            STG_B(0, 1, ktn0);
            asm volatile("s_waitcnt vmcnt(4)" ::: "memory");
            BARSEQ
            MFMAQ(3, a00, a01, a10, a11)
        }
        // ---- P5: B(buf1) + A(buf1,q0); stage A0 slices 0,2' ----
        {
            LDB8(1)
            LDA4(1, 0, a00, a01, a10, a11)
            STG_AS(0, 0, ktn0); STG_AS(0, 2, ktn0);
            BARSEQ
            MFMAQ(0, a00, a01, a10, a11)
        }
        // ---- P6: A(buf1,q1); stage A0 slices 1,3' ----
        {
            LDA4(1, 1, a00, a01, a10, a11)
            STG_AS(0, 1, ktn0); STG_AS(0, 3, ktn0);
            BARSEQ
            MFMAQ(1, a00, a01, a10, a11)
        }
        // ---- P7: A(buf1,q2); stage B1h0' ----
        {
            LDA4(1, 2, a00, a01, a10, a11)
            STG_B(1, 0, ktn1);
            BARSEQ
            MFMAQ(2, a00, a01, a10, a11)
        }
        // ---- P8: A(buf1,q3); stage B1h1'; GATE vmcnt(4) -> buf0' fully landed ----
        {
            LDA4(1, 3, a00, a01, a10, a11)
            STG_B(1, 1, ktn1);
            asm volatile("s_waitcnt vmcnt(4)" ::: "memory");
            BARSEQ
            MFMAQ(3, a00, a01, a10, a11)
        }
    }

    // drain in-flight dead stages before workgroup teardown
    asm volatile("s_waitcnt vmcnt(0)" ::: "memory");

    // ---- epilogue: bias + fp32 store (acc[m] row = 128wr + 16m + 4hi + r) ----
    const int rbase = tm * 256 + wr * 128;
    const int cbase = tn * 256 + wc * 64;
    float bv0 = bias[cbase + 0 * 16 + lo];
    float bv1 = bias[cbase + 1 * 16 + lo];
    float bv2 = bias[cbase + 2 * 16 + lo];
    float bv3 = bias[cbase + 3 * 16 + lo];
#pragma unroll
    for (int m = 0; m < 8; ++m) {
        const int r0r = rbase + m * 16 + hi * 4;
#pragma unroll
        for (int r = 0; r < 4; ++r) {
            float* crow = C + (size_t)(r0r + r) * Ndim + cbase + lo;
            crow[0]  = acc[m][0][r] + bv0;
            crow[16] = acc[m][1][r] + bv1;
            crow[32] = acc[m][2][r] + bv2;
            crow[48] = acc[m][3][r] + bv3;
        }
    }
}

// ---------------------------------------------------------------------------
extern "C" void kernel_launch(void* const* d_in, const int* in_sizes, int n_in,
                              void* d_out, int out_size, void* d_ws, size_t ws_size,
                              hipStream_t stream) {
    const float* x = (const float*)d_in[0];
    const float* w = (const float*)d_in[1];
    const float* bias = (const float*)d_in[2];
    float* out = (float*)d_out;

    if (in_sizes[2] != Ndim || in_sizes[1] != Ndim * Kdim || in_sizes[0] != Mdim * Kdim)
        return;  // shape-specialized; fail loudly

    const size_t xq_bytes = (size_t)Mdim * Kdim * sizeof(half_t);
    const size_t wq_bytes = (size_t)Ndim * Kdim * sizeof(half_t);
    if (ws_size < xq_bytes + wq_bytes) return;

    half_t* xq = (half_t*)d_ws;
    half_t* wq = (half_t*)((char*)d_ws + xq_bytes);

    // one merged quant launch: y-blocks [0,64) -> x, [64,96) -> w
    quant_kernel<<<dim3(Kdim / 128, Mdim / 128 + Ndim / 128), 256, 0, stream>>>(
        x, w, xq, wq, Kdim);

    (void)hipFuncSetAttribute((const void*)gemm_kernel,
                              hipFuncAttributeMaxDynamicSharedMemorySize, LDS_BYTES);

    gemm_kernel<<<dim3(NTM * NTN), dim3(512), LDS_BYTES, stream>>>(xq, wq, bias, out);
}